// Round 15
// baseline (294.501 us; speedup 1.0000x reference)
//
#include <hip/hip_runtime.h>
#include <hip/hip_bf16.h>

typedef unsigned short u16;
typedef float f32x4 __attribute__((ext_vector_type(4)));
typedef __bf16 bf16x8 __attribute__((ext_vector_type(8)));

#define BB 4
#define SS 2048
#define DD 1024
#define HH 16
#define HDD 64
#define MM (BB*SS)   // 8192

__device__ __forceinline__ u16 f2bf(float f){
    union { float f; unsigned int i; } v; v.f = f;
    unsigned int i = v.i;
    return (u16)((i + 0x7FFFu + ((i >> 16) & 1u)) >> 16);
}
__device__ __forceinline__ ushort2 pk2(float a, float b){
    union { __hip_bfloat162 h; ushort2 u; } v;
    float2 t; t.x = a; t.y = b;
    v.h = __float22bfloat162_rn(t);
    return v.u;
}
__device__ __forceinline__ ushort4 pk4(float a, float b, float c, float d){
    ushort2 lo = pk2(a, b), hi = pk2(c, d);
    ushort4 r; r.x = lo.x; r.y = lo.y; r.z = hi.x; r.w = hi.y;
    return r;
}
__device__ __forceinline__ void gl2lds16(const void* g, void* l){
    __builtin_amdgcn_global_load_lds(
        (const __attribute__((address_space(1))) void*)g,
        (__attribute__((address_space(3))) void*)l, 16, 0, 0);
}

__device__ __forceinline__ void cvt8(const float* __restrict__ src,
                                     u16* __restrict__ dst, size_t i)
{
    const float4 a = *(const float4*)&src[i];
    const float4 b = *(const float4*)&src[i + 4];
    ushort4 lo = pk4(a.x, a.y, a.z, a.w);
    ushort4 hi = pk4(b.x, b.y, b.z, b.w);
    uint4 o;
    o.x = (unsigned)lo.x | ((unsigned)lo.y << 16);
    o.y = (unsigned)lo.z | ((unsigned)lo.w << 16);
    o.z = (unsigned)hi.x | ((unsigned)hi.y << 16);
    o.w = (unsigned)hi.z | ((unsigned)hi.w << 16);
    *(uint4*)&dst[i] = o;
}

// ---------------- merged convert: x + Wq,Wk,Wv in ONE dispatch (R23) ----------------
__global__ __launch_bounds__(256) void cvtall_k(
    const float* __restrict__ x,
    const float* __restrict__ W0, const float* __restrict__ W1,
    const float* __restrict__ W2,
    u16* __restrict__ xb, u16* __restrict__ wscr)
{
    const size_t unit = (size_t)blockIdx.x * 256 + threadIdx.x;
    const size_t NU = (size_t)MM * DD / 8;       // 1,048,576 x-units
    const size_t WU = (size_t)DD * DD / 8;       //   131,072 W-units
    if (unit < NU) {
        cvt8(x, xb, unit * 8);
    } else {
        const size_t wu = unit - NU;
        const int wsel = (int)(wu >> 17);        // / 131072
        const size_t off = (wu & (WU - 1)) * 8;
        const float* src = wsel == 0 ? W0 : (wsel == 1 ? W1 : W2);
        cvt8(src, wscr + (size_t)wsel * DD * DD, off);
    }
}

// Wo -> bf16 (after attn_k, into the then-dead Q buffer)
__global__ __launch_bounds__(256) void cvtw1_k(const float* __restrict__ W,
                                               u16* __restrict__ dst)
{
    const size_t i = ((size_t)blockIdx.x * 256 + threadIdx.x) * 8;
    cvt8(W, dst, i);
}

// ---------------- GEMM core R24: C^T[n][m], 128n x 128m, 256 thr, 4 waves ----------------
// R23 post-mortem: qkv at ~20% MfmaUtil with 2 blocks/CU -- correlated barrier
// drains (same lesson as attn R18/R19, where 4 independent blocks/CU gave
// 139->123.6). Shrink to 128x128/256thr: LDS 32 KB -> 4 blocks/CU, four
// decorrelated barrier groups hide each other's vmcnt(0) windows.
// Same DMA staging, same proven 2-phase loop, same C^T epilogue mapping
// (wn2 = w&1, wm2 = w>>1; per-wave 64x64, acc[4][4] unchanged).
__device__ __forceinline__ void gemm_core(const u16* __restrict__ Wb,  // [1024n][K]
                                          const u16* __restrict__ Act, // [M][K]
                                          f32x4 (&acc)[4][4],
                                          u16 (&At)[2][128 * 32],
                                          u16 (&Bt)[2][128 * 32],
                                          int n0, int m0, int tid)
{
    const int lane = tid & 63, w = tid >> 6;   // w in 0..3
    const int quad = lane >> 4, l15 = lane & 15;
    const int wn2 = w & 1, wm2 = w >> 1;       // wave -> (n 64-block, m 64-block)
    const int arow = lane >> 2;                // 0..15 within 16-row chunk
    const int acol = (lane & 3) * 8;           // element offset (16B)

    auto STG = [&](int bi, int kt) {
        const int kk = kt * 32;
        // 16 1KB chunks: 0..7 -> At (128 n-rows), 8..15 -> Bt (128 m-rows)
        #pragma unroll
        for (int c0 = 0; c0 < 4; ++c0) {
            const int c = w * 4 + c0;               // wave-uniform
            if (c < 8) {
                gl2lds16(&Wb[(size_t)(n0 + c * 16 + arow) * DD + kk + acol],
                         &At[bi][c * 512]);
            } else {
                const int cb = c - 8;
                gl2lds16(&Act[(size_t)(m0 + cb * 16 + arow) * DD + kk + acol],
                         &Bt[bi][cb * 512]);
            }
        }
    };
    auto CMP = [&](int bi) {
        bf16x8 af[4], bfr[4];
        #pragma unroll
        for (int i = 0; i < 4; ++i)   // n-frags
            af[i] = *(const bf16x8*)&At[bi][(wn2 * 64 + i * 16 + l15) * 32 + quad * 8];
        #pragma unroll
        for (int j = 0; j < 4; ++j)   // m-frags
            bfr[j] = *(const bf16x8*)&Bt[bi][(wm2 * 64 + j * 16 + l15) * 32 + quad * 8];
        #pragma unroll
        for (int i = 0; i < 4; ++i)
            #pragma unroll
            for (int j = 0; j < 4; ++j)
                acc[i][j] = __builtin_amdgcn_mfma_f32_16x16x32_bf16(af[i], bfr[j], acc[i][j], 0, 0, 0);
    };

    STG(0, 0);
    __syncthreads();
    #pragma unroll 1
    for (int i = 0; i < 15; ++i) {   // K=1024 -> 32 tiles of BK=32
        STG(1, 2 * i + 1);
        CMP(0);
        __syncthreads();
        STG(0, 2 * i + 2);
        CMP(1);
        __syncthreads();
    }
    STG(1, 31);
    CMP(0);
    __syncthreads();
    CMP(1);
}

// QKV projection: z selects q/k/v. Q,K scattered to [B,H,S,HD] bf16;
// V written TRANSPOSED [B,H,HD,S] so attn stages it via async DMA (R20).
__global__ __launch_bounds__(256, 2) void gemm_qkv_k(
    const u16* __restrict__ x,
    const float* __restrict__ bq, const float* __restrict__ bk,
    const float* __restrict__ bv,
    const u16* __restrict__ Wqb, const u16* __restrict__ Wkb,
    const u16* __restrict__ Wvb,
    u16* __restrict__ Q, u16* __restrict__ K, u16* __restrict__ V)
{
    __shared__ alignas(16) u16 At[2][128 * 32];   // 16 KB
    __shared__ alignas(16) u16 Bt[2][128 * 32];   // 16 KB -> 32 KB total
    const int tid = threadIdx.x, lane = tid & 63, w = tid >> 6;
    const int quad = lane >> 4, l15 = lane & 15;
    const int wn2 = w & 1, wm2 = w >> 1;
    const int z = blockIdx.z;
    const u16* Wmb = z == 0 ? Wqb : (z == 1 ? Wkb : Wvb);
    const float* bias = z == 0 ? bq : (z == 1 ? bk : bv);
    u16* Out = z == 0 ? Q : (z == 1 ? K : V);
    const int m0 = blockIdx.x * 128, n0 = blockIdx.y * 128;

    f32x4 acc[4][4];
    #pragma unroll
    for (int i = 0; i < 4; ++i)
        #pragma unroll
        for (int j = 0; j < 4; ++j) acc[i][j] = (f32x4)(0.0f);

    gemm_core(Wmb, x, acc, At, Bt, n0, m0, tid);

    f32x4 bsv[4];
    #pragma unroll
    for (int i = 0; i < 4; ++i)
        bsv[i] = *(const f32x4*)&bias[n0 + wn2 * 64 + i * 16 + quad * 4];

    const int b = m0 / SS;
    const int h = (n0 + wn2 * 64) / HDD;         // hd block = 64 = one head
    const size_t base = ((size_t)(b * HH + h)) * SS * HDD;
    if (z == 2) {
        // V^T: [bh][hd][s]; hd = i*16+quad*4+r, s = m0%SS + wm2*64 + j*16 + l15
        #pragma unroll
        for (int i = 0; i < 4; ++i) {
            #pragma unroll
            for (int r = 0; r < 4; ++r) {
                const int hd = i * 16 + quad * 4 + r;
                const float bb = bsv[i][r];
                #pragma unroll
                for (int j = 0; j < 4; ++j) {
                    const int s = (m0 % SS) + wm2 * 64 + j * 16 + l15;
                    Out[base + (size_t)hd * SS + s] = f2bf(acc[i][j][r] + bb);
                }
            }
        }
    } else {
        #pragma unroll
        for (int j = 0; j < 4; ++j) {
            const int s = (m0 % SS) + wm2 * 64 + j * 16 + l15;
            #pragma unroll
            for (int i = 0; i < 4; ++i) {
                *(ushort4*)&Out[base + (size_t)s * HDD + i * 16 + quad * 4] =
                    pk4(acc[i][j][0] + bsv[i][0], acc[i][j][1] + bsv[i][1],
                        acc[i][j][2] + bsv[i][2], acc[i][j][3] + bsv[i][3]);
            }
        }
    }
}

// Output projection: A=Wo bf16, B=attn-out bf16, out fp32 [M,N] (float4 stores)
__global__ __launch_bounds__(256, 2) void gemm_out_k(
    const u16* __restrict__ A, const float* __restrict__ bo,
    const u16* __restrict__ Wob, float* __restrict__ Out)
{
    __shared__ alignas(16) u16 At[2][128 * 32];
    __shared__ alignas(16) u16 Bt[2][128 * 32];
    const int tid = threadIdx.x, lane = tid & 63, w = tid >> 6;
    const int quad = lane >> 4, l15 = lane & 15;
    const int wn2 = w & 1, wm2 = w >> 1;
    const int m0 = blockIdx.x * 128, n0 = blockIdx.y * 128;

    f32x4 acc[4][4];
    #pragma unroll
    for (int i = 0; i < 4; ++i)
        #pragma unroll
        for (int j = 0; j < 4; ++j) acc[i][j] = (f32x4)(0.0f);

    gemm_core(Wob, A, acc, At, Bt, n0, m0, tid);

    f32x4 bsv[4];
    #pragma unroll
    for (int i = 0; i < 4; ++i)
        bsv[i] = *(const f32x4*)&bo[n0 + wn2 * 64 + i * 16 + quad * 4];

    #pragma unroll
    for (int j = 0; j < 4; ++j) {
        const int m = m0 + wm2 * 64 + j * 16 + l15;
        #pragma unroll
        for (int i = 0; i < 4; ++i) {
            float4 f;
            f.x = acc[i][j][0] + bsv[i][0];
            f.y = acc[i][j][1] + bsv[i][1];
            f.z = acc[i][j][2] + bsv[i][2];
            f.w = acc[i][j][3] + bsv[i][3];
            *(float4*)&Out[(size_t)m * DD + n0 + wn2 * 64 + i * 16 + quad * 4] = f;
        }
    }
}

// ---------------- Flash attention (byte-identical to R20/R23, best measured) ----------------
#define QT 128
#define KT 64

#define LOG2E 1.4426950408889634f

__device__ __forceinline__ int swz128(int row, int bcol){
    return row * 128 + (bcol ^ ((row & 7) << 4));   // byte offset, rows of 128B
}

__global__ __launch_bounds__(256, 2) void attn_k(
    const u16* __restrict__ Q, const u16* __restrict__ K,
    const u16* __restrict__ V, const int* __restrict__ mask,
    u16* __restrict__ AO)
{
    __shared__ alignas(16) u16 QPs[QT * 64];    // 16384 B, swizzled: Q tile then P
    __shared__ alignas(16) u16 Ks[KT * 64];     //  8192 B, swizzled
    __shared__ alignas(16) u16 Vs[KT * 64];     //  8192 B, swizzled [hd][kpos]
    __shared__ float padf[KT];                  //   256 B (additive bias)
    // total 33024 B -> 4 blocks/CU x 4 waves = 16 waves/CU, 4 independent blocks

    const int tid = threadIdx.x, lane = tid & 63, w = tid >> 6;   // w in 0..3
    const int quad = lane >> 4, l15 = lane & 15;
    const int bh = blockIdx.x;
    const int y = blockIdx.y;
    const int qt = (y < 8) ? (15 - y) : (y - 8);  // pairs (15,0)(14,1)...(8,7)
    const int b = bh >> 4, h = bh & 15;
    const int q0 = qt * QT;
    const size_t hoff = (size_t)bh * SS * HDD;
    const u16* Qh = Q + hoff;
    const u16* Kh = K + hoff;
    const u16* Vt = V + hoff;                   // V^T: [hd][s], row stride SS
    const int nkt = (q0 + QT) / KT;
    const float scale2 = 0.125f * LOG2E;   // HD^-0.5 folded with log2(e)
    const int wrow_end = q0 + w * 32 + 32; // one past the wave's last q-row

    // DMA geometry (constant): chunk c covers rows c*8+vrow; source 16B col
    // inverse-swizzled so swz128-reads see [row][col].
    const int vrow = lane >> 3;                       // 0..7
    const int dbcol = (((lane & 7) ^ vrow) << 4);     // swizzled 16B slot

    // stage Q tile (swizzled rows of 128B): 1024 uint4 / 256 thr = 4 each
    for (int c = tid; c < QT * 8; c += 256) {
        const int row = c >> 3, cc = c & 7;
        *(uint4*)((char*)QPs + swz128(row, cc * 16)) =
            *(const uint4*)&Qh[(size_t)(q0 + row) * HDD + cc * 8];
    }
    __syncthreads();

    bf16x8 bQ[2][2];
    #pragma unroll
    for (int j = 0; j < 2; ++j)
        #pragma unroll
        for (int ks = 0; ks < 2; ++ks)
            bQ[j][ks] = *(const bf16x8*)((const char*)QPs +
                swz128(w * 32 + j * 16 + l15, ks * 64 + quad * 16));
    // QPs rows w*32..w*32+31 are wave-private from here on.

    float m_run[2] = { -1e30f, -1e30f };
    float l_run[2] = { 0.f, 0.f };     // per-quad partials
    f32x4 o[4][2];
    #pragma unroll
    for (int i = 0; i < 4; ++i)
        #pragma unroll
        for (int j = 0; j < 2; ++j) o[i][j] = (f32x4)(0.0f);

    // mask prefetch (1 tile deep): pm holds tile kt's mask value for tid<64
    int pm = 1;
    if (tid < KT) pm = mask[b * SS + tid];

    for (int kt = 0; kt < nkt; ++kt) {
        const int kt0 = kt * KT;
        __syncthreads();   // prior iter's Ks/Vs reads complete

        // K + V^T: async DMA, 4 instr/wave; barrier-2's vmcnt(0) drains them
        #pragma unroll
        for (int c0 = 0; c0 < 2; ++c0) {
            const int c = w * 2 + c0;     // 0..7, wave-uniform
            gl2lds16((const char*)Kh + (size_t)(kt0 + c * 8 + vrow) * 128 + dbcol,
                     (char*)Ks + c * 1024);
            gl2lds16((const char*)Vt + ((size_t)(c * 8 + vrow) * SS + kt0) * 2 + dbcol,
                     (char*)Vs + c * 1024);
        }
        if (tid < KT) padf[tid] = (pm == 0) ? -1e9f : 0.0f;
        __syncthreads();

        // prefetch next tile's mask during compute (latency hidden)
        if (tid < KT && kt + 1 < nkt) pm = mask[b * SS + kt0 + KT + tid];

        if (kt0 < wrow_end) {   // wave-uniform: tile has >=1 unmasked (row,col)
        // S^T = K Q^T : C[kpos = i*16+quad*4+r][qrow = w*32+j*16+l15]
        f32x4 sc[4][2];
        #pragma unroll
        for (int i = 0; i < 4; ++i)
            #pragma unroll
            for (int j = 0; j < 2; ++j) sc[i][j] = (f32x4)(0.0f);
        __builtin_amdgcn_s_setprio(1);
        #pragma unroll
        for (int ks = 0; ks < 2; ++ks) {
            bf16x8 aK[4];
            #pragma unroll
            for (int i = 0; i < 4; ++i)
                aK[i] = *(const bf16x8*)((const char*)Ks +
                    swz128(i * 16 + l15, ks * 64 + quad * 16));
            #pragma unroll
            for (int i = 0; i < 4; ++i)
                #pragma unroll
                for (int j = 0; j < 2; ++j)
                    sc[i][j] = __builtin_amdgcn_mfma_f32_16x16x32_bf16(aK[i], bQ[j][ks], sc[i][j], 0, 0, 0);
        }
        __builtin_amdgcn_s_setprio(0);

        f32x4 pb[4];
        #pragma unroll
        for (int i = 0; i < 4; ++i)
            pb[i] = *(const f32x4*)&padf[i * 16 + quad * 4];

        #pragma unroll
        for (int j = 0; j < 2; ++j) {
            const int qrow = q0 + w * 32 + j * 16 + l15;
            const bool needC = (kt0 + KT - 1) > (q0 + w * 32 + j * 16);  // wave-uniform
            float mx = -1e9f;
            if (needC) {
                #pragma unroll
                for (int i = 0; i < 4; ++i)
                    #pragma unroll
                    for (int r = 0; r < 4; ++r) {
                        const int kpg = kt0 + i * 16 + quad * 4 + r;
                        float s = fmaf(sc[i][j][r], scale2, pb[i][r]);
                        s = (kpg > qrow) ? -1e9f : s;
                        sc[i][j][r] = s; mx = fmaxf(mx, s);
                    }
            } else {
                #pragma unroll
                for (int i = 0; i < 4; ++i)
                    #pragma unroll
                    for (int r = 0; r < 4; ++r) {
                        float s = fmaf(sc[i][j][r], scale2, pb[i][r]);
                        sc[i][j][r] = s; mx = fmaxf(mx, s);
                    }
            }
            mx = fmaxf(mx, __shfl_xor(mx, 16, 64));
            mx = fmaxf(mx, __shfl_xor(mx, 32, 64));
            // defer-max (T13): skip rescale while max grows < 8 (log2 units)
            float nm = m_run[j];
            if (!__all(mx <= nm + 8.f)) {
                nm = fmaxf(nm, mx);
                const float alpha = __builtin_exp2f(m_run[j] - nm);
                m_run[j] = nm;
                l_run[j] *= alpha;
                #pragma unroll
                for (int i = 0; i < 4; ++i)
                    #pragma unroll
                    for (int r = 0; r < 4; ++r) o[i][j][r] *= alpha;
            }
            float rs = 0.f;
            #pragma unroll
            for (int i = 0; i < 4; ++i) {
                float p0 = __builtin_exp2f(sc[i][j][0] - nm);
                float p1 = __builtin_exp2f(sc[i][j][1] - nm);
                float p2 = __builtin_exp2f(sc[i][j][2] - nm);
                float p3 = __builtin_exp2f(sc[i][j][3] - nm);
                rs += (p0 + p1) + (p2 + p3);
                *(ushort4*)((char*)QPs + swz128(w * 32 + j * 16 + l15, i * 32 + quad * 8)) =
                    pk4(p0, p1, p2, p3);
            }
            l_run[j] += rs;
        }
        // same-wave LDS RAW (QPs writes -> bP reads)
        asm volatile("s_waitcnt lgkmcnt(0)" ::: "memory");

        // O^T += V^T P^T : A = Vs[hd][kpos] (swizzled), B = QPs[qrow][kpos]
        __builtin_amdgcn_s_setprio(1);
        #pragma unroll
        for (int ks = 0; ks < 2; ++ks) {
            bf16x8 aV[4], bP[2];
            #pragma unroll
            for (int i = 0; i < 4; ++i)
                aV[i] = *(const bf16x8*)((const char*)Vs +
                    swz128(i * 16 + l15, ks * 64 + quad * 16));
            #pragma unroll
            for (int j = 0; j < 2; ++j)
                bP[j] = *(const bf16x8*)((const char*)QPs +
                    swz128(w * 32 + j * 16 + l15, ks * 64 + quad * 16));
            #pragma unroll
            for (int i = 0; i < 4; ++i)
                #pragma unroll
                for (int j = 0; j < 2; ++j)
                    o[i][j] = __builtin_amdgcn_mfma_f32_16x16x32_bf16(aV[i], bP[j], o[i][j], 0, 0, 0);
        }
        __builtin_amdgcn_s_setprio(0);
        }   // if active tile
    }

    // final l reduction across quads, then store O^T -> AO [B,S,H*HD] (bf16)
    #pragma unroll
    for (int j = 0; j < 2; ++j) {
        float l = l_run[j];
        l += __shfl_xor(l, 16, 64);
        l += __shfl_xor(l, 32, 64);
        const float inv = (l > 0.f) ? (1.f / l) : 0.f;
        const int s = q0 + w * 32 + j * 16 + l15;
        const size_t rb = ((size_t)(b * SS + s)) * DD + h * HDD;
        #pragma unroll
        for (int i = 0; i < 4; ++i)
            *(ushort4*)&AO[rb + i * 16 + quad * 4] =
                pk4(o[i][j][0] * inv, o[i][j][1] * inv, o[i][j][2] * inv, o[i][j][3] * inv);
    }
}

extern "C" void kernel_launch(void* const* d_in, const int* in_sizes, int n_in,
                              void* d_out, int out_size, void* d_ws, size_t ws_size,
                              hipStream_t stream)
{
    const float* x  = (const float*)d_in[0];
    const int* mask = (const int*)d_in[1];
    const float* Wq = (const float*)d_in[2];
    const float* bq = (const float*)d_in[3];
    const float* Wk = (const float*)d_in[4];
    const float* bk = (const float*)d_in[5];
    const float* Wv = (const float*)d_in[6];
    const float* bv = (const float*)d_in[7];
    const float* Wo = (const float*)d_in[8];
    const float* bo = (const float*)d_in[9];
    float* out = (float*)d_out;

    u16* ws = (u16*)d_ws;
    const size_t NE = (size_t)MM * DD;
    const size_t WE = (size_t)DD * DD;
    if (ws_size < 4 * NE * sizeof(u16)) return;

    u16* Qb = ws;
    u16* Kb = ws + NE;
    u16* Vb = ws + 2 * NE;   // holds V^T [B,H,HD,S]
    u16* Ab = ws + 3 * NE;   // x_bf16 first, then attention output (sequential reuse)

    // W bf16 scratch lives in d_out (dead until gemm_out_k overwrites all of it)
    u16* Wscr = (u16*)d_out;          // Wq,Wk,Wv bf16: 6 MB <= 32 MB

    const size_t units = NE / 8 + 3 * (WE / 8);   // 1,441,792 -> 5632 blocks
    cvtall_k<<<dim3((unsigned)(units / 256)), dim3(256), 0, stream>>>(
        x, Wq, Wk, Wv, Ab, Wscr);
    gemm_qkv_k<<<dim3(MM / 128, DD / 128, 3), dim3(256), 0, stream>>>(
        Ab, bq, bk, bv, Wscr, Wscr + WE, Wscr + 2 * WE, Qb, Kb, Vb);
    attn_k<<<dim3(BB * HH, SS / QT), dim3(256), 0, stream>>>(Qb, Kb, Vb, mask, Ab);
    cvtw1_k<<<dim3(WE / 2048), dim3(256), 0, stream>>>(Wo, Qb);   // Q dead; holds Wo bf16
    gemm_out_k<<<dim3(MM / 128, DD / 128), dim3(256), 0, stream>>>(Ab, bo, Qb, out);
}

// Round 17
// 292.978 us; speedup vs baseline: 1.0052x; 1.0052x over previous
//
#include <hip/hip_runtime.h>
#include <hip/hip_bf16.h>

typedef unsigned short u16;
typedef float f32x4 __attribute__((ext_vector_type(4)));
typedef __bf16 bf16x8 __attribute__((ext_vector_type(8)));

#define BB 4
#define SS 2048
#define DD 1024
#define HH 16
#define HDD 64
#define MM (BB*SS)   // 8192

__device__ __forceinline__ u16 f2bf(float f){
    union { float f; unsigned int i; } v; v.f = f;
    unsigned int i = v.i;
    return (u16)((i + 0x7FFFu + ((i >> 16) & 1u)) >> 16);
}
__device__ __forceinline__ ushort2 pk2(float a, float b){
    union { __hip_bfloat162 h; ushort2 u; } v;
    float2 t; t.x = a; t.y = b;
    v.h = __float22bfloat162_rn(t);
    return v.u;
}
__device__ __forceinline__ ushort4 pk4(float a, float b, float c, float d){
    ushort2 lo = pk2(a, b), hi = pk2(c, d);
    ushort4 r; r.x = lo.x; r.y = lo.y; r.z = hi.x; r.w = hi.y;
    return r;
}
__device__ __forceinline__ void gl2lds16(const void* g, void* l){
    __builtin_amdgcn_global_load_lds(
        (const __attribute__((address_space(1))) void*)g,
        (__attribute__((address_space(3))) void*)l, 16, 0, 0);
}

__device__ __forceinline__ void cvt8(const float* __restrict__ src,
                                     u16* __restrict__ dst, size_t i)
{
    const float4 a = *(const float4*)&src[i];
    const float4 b = *(const float4*)&src[i + 4];
    ushort4 lo = pk4(a.x, a.y, a.z, a.w);
    ushort4 hi = pk4(b.x, b.y, b.z, b.w);
    uint4 o;
    o.x = (unsigned)lo.x | ((unsigned)lo.y << 16);
    o.y = (unsigned)lo.z | ((unsigned)lo.w << 16);
    o.z = (unsigned)hi.x | ((unsigned)hi.y << 16);
    o.w = (unsigned)hi.z | ((unsigned)hi.w << 16);
    *(uint4*)&dst[i] = o;
}

// ---------------- merged convert: x + Wq,Wk,Wv in ONE dispatch (R23) ----------------
__global__ __launch_bounds__(256) void cvtall_k(
    const float* __restrict__ x,
    const float* __restrict__ W0, const float* __restrict__ W1,
    const float* __restrict__ W2,
    u16* __restrict__ xb, u16* __restrict__ wscr)
{
    const size_t unit = (size_t)blockIdx.x * 256 + threadIdx.x;
    const size_t NU = (size_t)MM * DD / 8;       // 1,048,576 x-units
    const size_t WU = (size_t)DD * DD / 8;       //   131,072 W-units
    if (unit < NU) {
        cvt8(x, xb, unit * 8);
    } else {
        const size_t wu = unit - NU;
        const int wsel = (int)(wu >> 17);        // / 131072
        const size_t off = (wu & (WU - 1)) * 8;
        const float* src = wsel == 0 ? W0 : (wsel == 1 ? W1 : W2);
        cvt8(src, wscr + (size_t)wsel * DD * DD, off);
    }
}

// Wo -> bf16 (after attn_k, into the then-dead Q buffer)
__global__ __launch_bounds__(256) void cvtw1_k(const float* __restrict__ W,
                                               u16* __restrict__ dst)
{
    const size_t i = ((size_t)blockIdx.x * 256 + threadIdx.x) * 8;
    cvt8(W, dst, i);
}

// ---------------- GEMM core R25: R24 structure + T5 setprio on MFMA ----------------
// R24 post-mortem: 4 independent blocks/CU was neutral for timing, but it
// creates the m191 regime (co-resident blocks at uncorrelated phases) where
// s_setprio paid on attn. Wrap the 16-MFMA cluster in setprio(1)/(0) so the
// CU scheduler favors MFMA-issuing waves over neighbors' staging waves.
// Everything else byte-identical to R24 (proven 2-phase DMA dbuf).
__device__ __forceinline__ void gemm_core(const u16* __restrict__ Wb,  // [1024n][K]
                                          const u16* __restrict__ Act, // [M][K]
                                          f32x4 (&acc)[4][4],
                                          u16 (&At)[2][128 * 32],
                                          u16 (&Bt)[2][128 * 32],
                                          int n0, int m0, int tid)
{
    const int lane = tid & 63, w = tid >> 6;   // w in 0..3
    const int quad = lane >> 4, l15 = lane & 15;
    const int wn2 = w & 1, wm2 = w >> 1;       // wave -> (n 64-block, m 64-block)
    const int arow = lane >> 2;                // 0..15 within 16-row chunk
    const int acol = (lane & 3) * 8;           // element offset (16B)

    auto STG = [&](int bi, int kt) {
        const int kk = kt * 32;
        // 16 1KB chunks: 0..7 -> At (128 n-rows), 8..15 -> Bt (128 m-rows)
        #pragma unroll
        for (int c0 = 0; c0 < 4; ++c0) {
            const int c = w * 4 + c0;               // wave-uniform
            if (c < 8) {
                gl2lds16(&Wb[(size_t)(n0 + c * 16 + arow) * DD + kk + acol],
                         &At[bi][c * 512]);
            } else {
                const int cb = c - 8;
                gl2lds16(&Act[(size_t)(m0 + cb * 16 + arow) * DD + kk + acol],
                         &Bt[bi][cb * 512]);
            }
        }
    };
    auto CMP = [&](int bi) {
        bf16x8 af[4], bfr[4];
        #pragma unroll
        for (int i = 0; i < 4; ++i)   // n-frags
            af[i] = *(const bf16x8*)&At[bi][(wn2 * 64 + i * 16 + l15) * 32 + quad * 8];
        #pragma unroll
        for (int j = 0; j < 4; ++j)   // m-frags
            bfr[j] = *(const bf16x8*)&Bt[bi][(wm2 * 64 + j * 16 + l15) * 32 + quad * 8];
        __builtin_amdgcn_s_setprio(1);
        #pragma unroll
        for (int i = 0; i < 4; ++i)
            #pragma unroll
            for (int j = 0; j < 4; ++j)
                acc[i][j] = __builtin_amdgcn_mfma_f32_16x16x32_bf16(af[i], bfr[j], acc[i][j], 0, 0, 0);
        __builtin_amdgcn_s_setprio(0);
    };

    STG(0, 0);
    __syncthreads();
    #pragma unroll 1
    for (int i = 0; i < 15; ++i) {   // K=1024 -> 32 tiles of BK=32
        STG(1, 2 * i + 1);
        CMP(0);
        __syncthreads();
        STG(0, 2 * i + 2);
        CMP(1);
        __syncthreads();
    }
    STG(1, 31);
    CMP(0);
    __syncthreads();
    CMP(1);
}

// QKV projection: z selects q/k/v. Q,K scattered to [B,H,S,HD] bf16;
// V written TRANSPOSED [B,H,HD,S] so attn stages it via async DMA (R20).
__global__ __launch_bounds__(256, 2) void gemm_qkv_k(
    const u16* __restrict__ x,
    const float* __restrict__ bq, const float* __restrict__ bk,
    const float* __restrict__ bv,
    const u16* __restrict__ Wqb, const u16* __restrict__ Wkb,
    const u16* __restrict__ Wvb,
    u16* __restrict__ Q, u16* __restrict__ K, u16* __restrict__ V)
{
    __shared__ alignas(16) u16 At[2][128 * 32];   // 16 KB
    __shared__ alignas(16) u16 Bt[2][128 * 32];   // 16 KB -> 32 KB total
    const int tid = threadIdx.x, lane = tid & 63, w = tid >> 6;
    const int quad = lane >> 4, l15 = lane & 15;
    const int wn2 = w & 1, wm2 = w >> 1;
    const int z = blockIdx.z;
    const u16* Wmb = z == 0 ? Wqb : (z == 1 ? Wkb : Wvb);
    const float* bias = z == 0 ? bq : (z == 1 ? bk : bv);
    u16* Out = z == 0 ? Q : (z == 1 ? K : V);
    const int m0 = blockIdx.x * 128, n0 = blockIdx.y * 128;

    f32x4 acc[4][4];
    #pragma unroll
    for (int i = 0; i < 4; ++i)
        #pragma unroll
        for (int j = 0; j < 4; ++j) acc[i][j] = (f32x4)(0.0f);

    gemm_core(Wmb, x, acc, At, Bt, n0, m0, tid);

    f32x4 bsv[4];
    #pragma unroll
    for (int i = 0; i < 4; ++i)
        bsv[i] = *(const f32x4*)&bias[n0 + wn2 * 64 + i * 16 + quad * 4];

    const int b = m0 / SS;
    const int h = (n0 + wn2 * 64) / HDD;         // hd block = 64 = one head
    const size_t base = ((size_t)(b * HH + h)) * SS * HDD;
    if (z == 2) {
        // V^T: [bh][hd][s]; hd = i*16+quad*4+r, s = m0%SS + wm2*64 + j*16 + l15
        #pragma unroll
        for (int i = 0; i < 4; ++i) {
            #pragma unroll
            for (int r = 0; r < 4; ++r) {
                const int hd = i * 16 + quad * 4 + r;
                const float bb = bsv[i][r];
                #pragma unroll
                for (int j = 0; j < 4; ++j) {
                    const int s = (m0 % SS) + wm2 * 64 + j * 16 + l15;
                    Out[base + (size_t)hd * SS + s] = f2bf(acc[i][j][r] + bb);
                }
            }
        }
    } else {
        #pragma unroll
        for (int j = 0; j < 4; ++j) {
            const int s = (m0 % SS) + wm2 * 64 + j * 16 + l15;
            #pragma unroll
            for (int i = 0; i < 4; ++i) {
                *(ushort4*)&Out[base + (size_t)s * HDD + i * 16 + quad * 4] =
                    pk4(acc[i][j][0] + bsv[i][0], acc[i][j][1] + bsv[i][1],
                        acc[i][j][2] + bsv[i][2], acc[i][j][3] + bsv[i][3]);
            }
        }
    }
}

// Output projection: A=Wo bf16, B=attn-out bf16, out fp32 [M,N] (float4 stores)
__global__ __launch_bounds__(256, 2) void gemm_out_k(
    const u16* __restrict__ A, const float* __restrict__ bo,
    const u16* __restrict__ Wob, float* __restrict__ Out)
{
    __shared__ alignas(16) u16 At[2][128 * 32];
    __shared__ alignas(16) u16 Bt[2][128 * 32];
    const int tid = threadIdx.x, lane = tid & 63, w = tid >> 6;
    const int quad = lane >> 4, l15 = lane & 15;
    const int wn2 = w & 1, wm2 = w >> 1;
    const int m0 = blockIdx.x * 128, n0 = blockIdx.y * 128;

    f32x4 acc[4][4];
    #pragma unroll
    for (int i = 0; i < 4; ++i)
        #pragma unroll
        for (int j = 0; j < 4; ++j) acc[i][j] = (f32x4)(0.0f);

    gemm_core(Wob, A, acc, At, Bt, n0, m0, tid);

    f32x4 bsv[4];
    #pragma unroll
    for (int i = 0; i < 4; ++i)
        bsv[i] = *(const f32x4*)&bo[n0 + wn2 * 64 + i * 16 + quad * 4];

    #pragma unroll
    for (int j = 0; j < 4; ++j) {
        const int m = m0 + wm2 * 64 + j * 16 + l15;
        #pragma unroll
        for (int i = 0; i < 4; ++i) {
            float4 f;
            f.x = acc[i][j][0] + bsv[i][0];
            f.y = acc[i][j][1] + bsv[i][1];
            f.z = acc[i][j][2] + bsv[i][2];
            f.w = acc[i][j][3] + bsv[i][3];
            *(float4*)&Out[(size_t)m * DD + n0 + wn2 * 64 + i * 16 + quad * 4] = f;
        }
    }
}

// ---------------- Flash attention (byte-identical to R20/R23/R24, best measured) ----------------
#define QT 128
#define KT 64

#define LOG2E 1.4426950408889634f

__device__ __forceinline__ int swz128(int row, int bcol){
    return row * 128 + (bcol ^ ((row & 7) << 4));   // byte offset, rows of 128B
}

__global__ __launch_bounds__(256, 2) void attn_k(
    const u16* __restrict__ Q, const u16* __restrict__ K,
    const u16* __restrict__ V, const int* __restrict__ mask,
    u16* __restrict__ AO)
{
    __shared__ alignas(16) u16 QPs[QT * 64];    // 16384 B, swizzled: Q tile then P
    __shared__ alignas(16) u16 Ks[KT * 64];     //  8192 B, swizzled
    __shared__ alignas(16) u16 Vs[KT * 64];     //  8192 B, swizzled [hd][kpos]
    __shared__ float padf[KT];                  //   256 B (additive bias)
    // total 33024 B -> 4 blocks/CU x 4 waves = 16 waves/CU, 4 independent blocks

    const int tid = threadIdx.x, lane = tid & 63, w = tid >> 6;   // w in 0..3
    const int quad = lane >> 4, l15 = lane & 15;
    const int bh = blockIdx.x;
    const int y = blockIdx.y;
    const int qt = (y < 8) ? (15 - y) : (y - 8);  // pairs (15,0)(14,1)...(8,7)
    const int b = bh >> 4, h = bh & 15;
    const int q0 = qt * QT;
    const size_t hoff = (size_t)bh * SS * HDD;
    const u16* Qh = Q + hoff;
    const u16* Kh = K + hoff;
    const u16* Vt = V + hoff;                   // V^T: [hd][s], row stride SS
    const int nkt = (q0 + QT) / KT;
    const float scale2 = 0.125f * LOG2E;   // HD^-0.5 folded with log2(e)
    const int wrow_end = q0 + w * 32 + 32; // one past the wave's last q-row

    // DMA geometry (constant): chunk c covers rows c*8+vrow; source 16B col
    // inverse-swizzled so swz128-reads see [row][col].
    const int vrow = lane >> 3;                       // 0..7
    const int dbcol = (((lane & 7) ^ vrow) << 4);     // swizzled 16B slot

    // stage Q tile (swizzled rows of 128B): 1024 uint4 / 256 thr = 4 each
    for (int c = tid; c < QT * 8; c += 256) {
        const int row = c >> 3, cc = c & 7;
        *(uint4*)((char*)QPs + swz128(row, cc * 16)) =
            *(const uint4*)&Qh[(size_t)(q0 + row) * HDD + cc * 8];
    }
    __syncthreads();

    bf16x8 bQ[2][2];
    #pragma unroll
    for (int j = 0; j < 2; ++j)
        #pragma unroll
        for (int ks = 0; ks < 2; ++ks)
            bQ[j][ks] = *(const bf16x8*)((const char*)QPs +
                swz128(w * 32 + j * 16 + l15, ks * 64 + quad * 16));
    // QPs rows w*32..w*32+31 are wave-private from here on.

    float m_run[2] = { -1e30f, -1e30f };
    float l_run[2] = { 0.f, 0.f };     // per-quad partials
    f32x4 o[4][2];
    #pragma unroll
    for (int i = 0; i < 4; ++i)
        #pragma unroll
        for (int j = 0; j < 2; ++j) o[i][j] = (f32x4)(0.0f);

    // mask prefetch (1 tile deep): pm holds tile kt's mask value for tid<64
    int pm = 1;
    if (tid < KT) pm = mask[b * SS + tid];

    for (int kt = 0; kt < nkt; ++kt) {
        const int kt0 = kt * KT;
        __syncthreads();   // prior iter's Ks/Vs reads complete

        // K + V^T: async DMA, 4 instr/wave; barrier-2's vmcnt(0) drains them
        #pragma unroll
        for (int c0 = 0; c0 < 2; ++c0) {
            const int c = w * 2 + c0;     // 0..7, wave-uniform
            gl2lds16((const char*)Kh + (size_t)(kt0 + c * 8 + vrow) * 128 + dbcol,
                     (char*)Ks + c * 1024);
            gl2lds16((const char*)Vt + ((size_t)(c * 8 + vrow) * SS + kt0) * 2 + dbcol,
                     (char*)Vs + c * 1024);
        }
        if (tid < KT) padf[tid] = (pm == 0) ? -1e9f : 0.0f;
        __syncthreads();

        // prefetch next tile's mask during compute (latency hidden)
        if (tid < KT && kt + 1 < nkt) pm = mask[b * SS + kt0 + KT + tid];

        if (kt0 < wrow_end) {   // wave-uniform: tile has >=1 unmasked (row,col)
        // S^T = K Q^T : C[kpos = i*16+quad*4+r][qrow = w*32+j*16+l15]
        f32x4 sc[4][2];
        #pragma unroll
        for (int i = 0; i < 4; ++i)
            #pragma unroll
            for (int j = 0; j < 2; ++j) sc[i][j] = (f32x4)(0.0f);
        __builtin_amdgcn_s_setprio(1);
        #pragma unroll
        for (int ks = 0; ks < 2; ++ks) {
            bf16x8 aK[4];
            #pragma unroll
            for (int i = 0; i < 4; ++i)
                aK[i] = *(const bf16x8*)((const char*)Ks +
                    swz128(i * 16 + l15, ks * 64 + quad * 16));
            #pragma unroll
            for (int i = 0; i < 4; ++i)
                #pragma unroll
                for (int j = 0; j < 2; ++j)
                    sc[i][j] = __builtin_amdgcn_mfma_f32_16x16x32_bf16(aK[i], bQ[j][ks], sc[i][j], 0, 0, 0);
        }
        __builtin_amdgcn_s_setprio(0);

        f32x4 pb[4];
        #pragma unroll
        for (int i = 0; i < 4; ++i)
            pb[i] = *(const f32x4*)&padf[i * 16 + quad * 4];

        #pragma unroll
        for (int j = 0; j < 2; ++j) {
            const int qrow = q0 + w * 32 + j * 16 + l15;
            const bool needC = (kt0 + KT - 1) > (q0 + w * 32 + j * 16);  // wave-uniform
            float mx = -1e9f;
            if (needC) {
                #pragma unroll
                for (int i = 0; i < 4; ++i)
                    #pragma unroll
                    for (int r = 0; r < 4; ++r) {
                        const int kpg = kt0 + i * 16 + quad * 4 + r;
                        float s = fmaf(sc[i][j][r], scale2, pb[i][r]);
                        s = (kpg > qrow) ? -1e9f : s;
                        sc[i][j][r] = s; mx = fmaxf(mx, s);
                    }
            } else {
                #pragma unroll
                for (int i = 0; i < 4; ++i)
                    #pragma unroll
                    for (int r = 0; r < 4; ++r) {
                        float s = fmaf(sc[i][j][r], scale2, pb[i][r]);
                        sc[i][j][r] = s; mx = fmaxf(mx, s);
                    }
            }
            mx = fmaxf(mx, __shfl_xor(mx, 16, 64));
            mx = fmaxf(mx, __shfl_xor(mx, 32, 64));
            // defer-max (T13): skip rescale while max grows < 8 (log2 units)
            float nm = m_run[j];
            if (!__all(mx <= nm + 8.f)) {
                nm = fmaxf(nm, mx);
                const float alpha = __builtin_exp2f(m_run[j] - nm);
                m_run[j] = nm;
                l_run[j] *= alpha;
                #pragma unroll
                for (int i = 0; i < 4; ++i)
                    #pragma unroll
                    for (int r = 0; r < 4; ++r) o[i][j][r] *= alpha;
            }
            float rs = 0.f;
            #pragma unroll
            for (int i = 0; i < 4; ++i) {
                float p0 = __builtin_exp2f(sc[i][j][0] - nm);
                float p1 = __builtin_exp2f(sc[i][j][1] - nm);
                float p2 = __builtin_exp2f(sc[i][j][2] - nm);
                float p3 = __builtin_exp2f(sc[i][j][3] - nm);
                rs += (p0 + p1) + (p2 + p3);
                *(ushort4*)((char*)QPs + swz128(w * 32 + j * 16 + l15, i * 32 + quad * 8)) =
                    pk4(p0, p1, p2, p3);
            }
            l_run[j] += rs;
        }
        // same-wave LDS RAW (QPs writes -> bP reads)
        asm volatile("s_waitcnt lgkmcnt(0)" ::: "memory");

        // O^T += V^T P^T : A = Vs[hd][kpos] (swizzled), B = QPs[qrow][kpos]
        __builtin_amdgcn_s_setprio(1);
        #pragma unroll
        for (int ks = 0; ks < 2; ++ks) {
            bf16x8 aV[4], bP[2];
            #pragma unroll
            for (int i = 0; i < 4; ++i)
                aV[i] = *(const bf16x8*)((const char*)Vs +
                    swz128(i * 16 + l15, ks * 64 + quad * 16));
            #pragma unroll
            for (int j = 0; j < 2; ++j)
                bP[j] = *(const bf16x8*)((const char*)QPs +
                    swz128(w * 32 + j * 16 + l15, ks * 64 + quad * 16));
            #pragma unroll
            for (int i = 0; i < 4; ++i)
                #pragma unroll
                for (int j = 0; j < 2; ++j)
                    o[i][j] = __builtin_amdgcn_mfma_f32_16x16x32_bf16(aV[i], bP[j], o[i][j], 0, 0, 0);
        }
        __builtin_amdgcn_s_setprio(0);
        }   // if active tile
    }

    // final l reduction across quads, then store O^T -> AO [B,S,H*HD] (bf16)
    #pragma unroll
    for (int j = 0; j < 2; ++j) {
        float l = l_run[j];
        l += __shfl_xor(l, 16, 64);
        l += __shfl_xor(l, 32, 64);
        const float inv = (l > 0.f) ? (1.f / l) : 0.f;
        const int s = q0 + w * 32 + j * 16 + l15;
        const size_t rb = ((size_t)(b * SS + s)) * DD + h * HDD;
        #pragma unroll
        for (int i = 0; i < 4; ++i)
            *(ushort4*)&AO[rb + i * 16 + quad * 4] =
                pk4(o[i][j][0] * inv, o[i][j][1] * inv, o[i][j][2] * inv, o[i][j][3] * inv);
    }
}

extern "C" void kernel_launch(void* const* d_in, const int* in_sizes, int n_in,
                              void* d_out, int out_size, void* d_ws, size_t ws_size,
                              hipStream_t stream)
{
    const float* x  = (const float*)d_in[0];
    const int* mask = (const int*)d_in[1];
    const float* Wq = (const float*)d_in[2];
    const float* bq = (const float*)d_in[3];
    const float* Wk = (const float*)d_in[4];
    const float* bk = (const float*)d_in[5];
    const float* Wv = (const float*)d_in[6];
    const float* bv = (const float*)d_in[7];
    const float* Wo = (const float*)d_in[8];
    const float* bo = (const float*)d_in[9];
    float* out = (float*)d_out;

    u16* ws = (u16*)d_ws;
    const size_t NE = (size_t)MM * DD;
    const size_t WE = (size_t)DD * DD;
    if (ws_size < 4 * NE * sizeof(u16)) return;

    u16* Qb = ws;
    u16* Kb = ws + NE;
    u16* Vb = ws + 2 * NE;   // holds V^T [B,H,HD,S]
    u16* Ab = ws + 3 * NE;   // x_bf16 first, then attention output (sequential reuse)

    // W bf16 scratch lives in d_out (dead until gemm_out_k overwrites all of it)
    u16* Wscr = (u16*)d_out;          // Wq,Wk,Wv bf16: 6 MB <= 32 MB

    const size_t units = NE / 8 + 3 * (WE / 8);   // 1,441,792 -> 5632 blocks
    cvtall_k<<<dim3((unsigned)(units / 256)), dim3(256), 0, stream>>>(
        x, Wq, Wk, Wv, Ab, Wscr);
    gemm_qkv_k<<<dim3(MM / 128, DD / 128, 3), dim3(256), 0, stream>>>(
        Ab, bq, bk, bv, Wscr, Wscr + WE, Wscr + 2 * WE, Qb, Kb, Vb);
    attn_k<<<dim3(BB * HH, SS / QT), dim3(256), 0, stream>>>(Qb, Kb, Vb, mask, Ab);
    cvtw1_k<<<dim3(WE / 2048), dim3(256), 0, stream>>>(Wo, Qb);   // Q dead; holds Wo bf16
    gemm_out_k<<<dim3(MM / 128, DD / 128), dim3(256), 0, stream>>>(Ab, bo, Qb, out);
}